// Round 9
// baseline (74.992 us; speedup 1.0000x reference)
//
#include <hip/hip_runtime.h>

// VOCAB=1e6, DIM=64, BAGS=16384, N_IDX=819200, CAT_DIM=128.
// Output row = [eb(64) | eb(64) | cat(128)] = 256 f32.
//
// R9 = R4 (best: 70us) with non-gather overhead stripped:
//  - CHUNK=100: 8192 waves = exactly 32/CU, single residency round
//    (R4 ran two rounds of 16384 waves); halves searches + flushes.
//  - init uses non-temporal loads/stores so its 24MB doesn't evict wq
//    rows from L3 (table=244MB ~ L3=256MB; protect gather reuse).
// Gather core unchanged: readlane->SGPR burst of 25 independent 256B row
// loads, wave-coalesced 256B atomics at bag boundaries.

constexpr int CHUNK = 100;
constexpr int GROUP = 25;

__device__ __forceinline__ float readlane_f(float x, int k) {
    return __int_as_float(__builtin_amdgcn_readlane(__float_as_int(x), k));
}

__device__ __forceinline__ int detect_sh(const unsigned int* p) {
    // int64 vs int32 layout (LE): high words of first 4 indices == 0.
    return ((p[1] | p[3] | p[5] | p[7]) == 0u) ? 1 : 0;
}

__global__ __launch_bounds__(256) void init_out_kernel(
    const float* __restrict__ cat, float* __restrict__ out, int total)
{
    int t = blockIdx.x * 256 + threadIdx.x;   // total = num_bags*256
    if (t >= total) return;
    int b = t >> 8, c = t & 255;
    float v = (c < 128) ? 0.0f
            : __builtin_nontemporal_load(cat + (b << 7) + (c - 128));
    __builtin_nontemporal_store(v, out + t);
}

__global__ __launch_bounds__(256) void embag_kernel(
    const int* __restrict__ wq,             // [VOCAB, 64] int32 codes
    const float* __restrict__ scales,       // [VOCAB]
    const float* __restrict__ biases,       // [VOCAB]
    const unsigned int* __restrict__ idx32, // indices viewed as u32 words
    const unsigned int* __restrict__ off32, // offsets viewed as u32 words
    float* __restrict__ out,                // [BAGS, 256]
    int num_bags, int n_idx)
{
    const int sh = detect_sh(idx32);
    const int lane = threadIdx.x & 63;
    const int wid  = blockIdx.x * 4 + (threadIdx.x >> 6);
    const long long base = (long long)wid * CHUNK;
    if (base >= n_idx) return;
    const int i0  = (int)base;
    const int cnt = min(CHUNK, n_idx - i0);

    // Per-lane prefetch of idx/scale/bias: rows 0..63 in A, 64..99 in B.
    const int liA = i0 + min(lane, cnt - 1);
    const int liB = i0 + min(64 + lane, cnt - 1);
    const int idxA = (int)idx32[(unsigned)liA << sh];
    const int idxB = (int)idx32[(unsigned)liB << sh];
    const float sA = scales[idxA], sB = scales[idxB];
    const float bA = biases[idxA], bB = biases[idxB];

    // Start bag: smallest b with off[b+1] > i0 (searchsorted-right).
    int lo = 0, hi = num_bags - 1;
    while (lo < hi) {
        int mid = (lo + hi) >> 1;
        if ((int)off32[(unsigned)(mid + 1) << sh] > i0) hi = mid; else lo = mid + 1;
    }
    int b = lo;
    int bend = (int)off32[(unsigned)(b + 1) << sh];

    float acc = 0.f, ab = 0.f;
    const char* wqb = (const char*)wq + (lane << 2);

    for (int g = 0; g < CHUNK; g += GROUP) {
        // Burst-issue GROUP independent 256B row gathers (readlane -> SGPR).
        int q[GROUP];
        #pragma unroll
        for (int k = 0; k < GROUP; ++k) {
            const int r = g + k;   // compile-time within unrolled loop
            const int ik = (r < 64) ? __builtin_amdgcn_readlane(idxA, r)
                                    : __builtin_amdgcn_readlane(idxB, r - 64);
            q[k] = *(const int*)(wqb + ((long long)ik << 8));
        }
        // Consume with boundary flushes.
        #pragma unroll
        for (int k = 0; k < GROUP; ++k) {
            const int r = g + k;
            const int j = i0 + r;
            if (j >= n_idx) break;
            if (j >= bend) {
                const float v = acc + ab;
                float* p = out + ((long long)b << 8) + lane;
                atomicAdd(p, v);
                atomicAdd(p + 64, v);
                acc = 0.f; ab = 0.f;
                do { ++b; bend = (int)off32[(unsigned)(b + 1) << sh]; } while (bend <= j);
            }
            const float s  = (r < 64) ? readlane_f(sA, r) : readlane_f(sB, r - 64);
            const float bi = (r < 64) ? readlane_f(bA, r) : readlane_f(bB, r - 64);
            acc = fmaf((float)q[k], s, acc);
            ab += bi;
        }
    }
    const float v = acc + ab;
    float* p = out + ((long long)b << 8) + lane;
    atomicAdd(p, v);
    atomicAdd(p + 64, v);
}

extern "C" void kernel_launch(void* const* d_in, const int* in_sizes, int n_in,
                              void* d_out, int out_size, void* d_ws, size_t ws_size,
                              hipStream_t stream) {
    const int*          wq     = (const int*)d_in[0];
    const float*        scales = (const float*)d_in[1];
    const float*        biases = (const float*)d_in[2];
    const unsigned int* idx32  = (const unsigned int*)d_in[3];
    const unsigned int* off32  = (const unsigned int*)d_in[4];
    const float*        cat    = (const float*)d_in[5];
    float*              out    = (float*)d_out;

    const int num_bags = in_sizes[5] / 128;       // 16384
    const int n_idx    = in_sizes[3];             // 819200

    const int total = num_bags * 256;
    init_out_kernel<<<(total + 255) / 256, 256, 0, stream>>>(cat, out, total);

    const int nchunks = (n_idx + CHUNK - 1) / CHUNK;   // 8192 waves
    const int blocks  = (nchunks + 3) / 4;             // 2048
    embag_kernel<<<blocks, 256, 0, stream>>>(
        wq, scales, biases, idx32, off32, out, num_bags, n_idx);
}

// Round 10
// 70.262 us; speedup vs baseline: 1.0673x; 1.0673x over previous
//
#include <hip/hip_runtime.h>

// VOCAB=1e6, DIM=64, BAGS=16384, N_IDX=819200, CAT_DIM=128.
// Output row = [eb(64) | eb(64) | cat(128)] = 256 f32.
//
// FINAL (= R4, best measured: 70.1 us). Roofline argument:
//   embag moves ~188 MB (near the ~165 MB byte minimum: 143 MB unique rows +
//   idx/scales/biases/cat) at the measured MI355X random-256B-gather rate of
//   ~3.0-3.2 TB/s -> ~62 us, + ~4 us init + launch overhead.
//   Rate shown insensitive to: burst depth 2->25 (R2~R4), bytes/VMEM-inst
//   256B->1KB (R5), atomic traffic 97->13MB (R3/R8), occupancy 32->68%,
//   residency shape (R9). Streaming conversion (repack) must read the full
//   256MB table per call -> strictly worse (R6/R7).
//
// Structure: wave-per-chunk (CHUNK=50, 819200=16384*50, perfect balance).
// Phase 1: per-lane prefetch of idx/scale/bias for the whole chunk.
// Phase 2: burst-issue 25 independent 256B row gathers via readlane->SGPR.
// Phase 3: unrolled consume; scale/bias broadcast via readlane;
//          wave-coalesced 256B atomics at bag boundaries.

constexpr int CHUNK = 50;
constexpr int GROUP = 25;

__device__ __forceinline__ float readlane_f(float x, int k) {
    return __int_as_float(__builtin_amdgcn_readlane(__float_as_int(x), k));
}

__global__ __launch_bounds__(256) void init_out_kernel(
    const float* __restrict__ cat, float* __restrict__ out, int total)
{
    int t = blockIdx.x * 256 + threadIdx.x;   // total = num_bags*256
    if (t >= total) return;
    int b = t >> 8, c = t & 255;
    out[t] = (c < 128) ? 0.0f : cat[(b << 7) + (c - 128)];
}

__global__ __launch_bounds__(256) void embag_kernel(
    const int* __restrict__ wq,             // [VOCAB, 64] int32 codes
    const float* __restrict__ scales,       // [VOCAB]
    const float* __restrict__ biases,       // [VOCAB]
    const unsigned int* __restrict__ idx32, // indices viewed as u32 words
    const unsigned int* __restrict__ off32, // offsets viewed as u32 words
    float* __restrict__ out,                // [BAGS, 256]
    int num_bags, int n_idx)
{
    // int64 vs int32 layout detection (LE): high words of first indices == 0.
    const bool is64 = ((idx32[1] | idx32[3] | idx32[5] | idx32[7]) == 0u);
    const int sh = is64 ? 1 : 0;

    const int lane = threadIdx.x & 63;
    const int wid  = blockIdx.x * 4 + (threadIdx.x >> 6);
    const long long base = (long long)wid * CHUNK;
    if (base >= n_idx) return;
    const int i0  = (int)base;
    const int cnt = min(CHUNK, n_idx - i0);

    // Phase 1: per-lane prefetch (lanes >= cnt clamp to last valid -> safe dup)
    const int li = i0 + min(lane, cnt - 1);
    const int myidx = (int)idx32[(unsigned)li << sh];
    const float mys = scales[myidx];
    const float myb = biases[myidx];

    // start bag: smallest b with off[b+1] > i0 (searchsorted-right semantics)
    int lo = 0, hi = num_bags - 1;
    while (lo < hi) {
        int mid = (lo + hi) >> 1;
        if ((int)off32[(unsigned)(mid + 1) << sh] > i0) hi = mid; else lo = mid + 1;
    }
    int b = lo;
    int bend = (int)off32[(unsigned)(b + 1) << sh];

    float acc = 0.f, ab = 0.f;
    const char* wqb = (const char*)wq + (lane << 2);

    for (int g = 0; g < CHUNK; g += GROUP) {
        // Phase 2: burst-issue GROUP independent row loads
        int q[GROUP];
        #pragma unroll
        for (int k = 0; k < GROUP; ++k) {
            const int ik = __builtin_amdgcn_readlane(myidx, g + k); // SGPR
            q[k] = *(const int*)(wqb + ((long long)ik << 8));       // 256B/wave
        }
        // Phase 3: consume with boundary flushes
        #pragma unroll
        for (int k = 0; k < GROUP; ++k) {
            const int j = i0 + g + k;
            if (j >= n_idx) break;
            if (j >= bend) {
                const float v = acc + ab;
                float* p = out + ((long long)b << 8) + lane;
                atomicAdd(p, v);        // eb1
                atomicAdd(p + 64, v);   // eb2 (identical sum)
                acc = 0.f; ab = 0.f;
                do { ++b; bend = (int)off32[(unsigned)(b + 1) << sh]; } while (bend <= j);
            }
            acc = fmaf((float)q[k], readlane_f(mys, g + k), acc);
            ab += readlane_f(myb, g + k);
        }
    }

    // final flush
    const float v = acc + ab;
    float* p = out + ((long long)b << 8) + lane;
    atomicAdd(p, v);
    atomicAdd(p + 64, v);
}

extern "C" void kernel_launch(void* const* d_in, const int* in_sizes, int n_in,
                              void* d_out, int out_size, void* d_ws, size_t ws_size,
                              hipStream_t stream) {
    const int*          wq     = (const int*)d_in[0];
    const float*        scales = (const float*)d_in[1];
    const float*        biases = (const float*)d_in[2];
    const unsigned int* idx32  = (const unsigned int*)d_in[3];
    const unsigned int* off32  = (const unsigned int*)d_in[4];
    const float*        cat    = (const float*)d_in[5];
    float*              out    = (float*)d_out;

    const int num_bags = in_sizes[5] / 128;       // 16384
    const int n_idx    = in_sizes[3];             // 819200

    const int total = num_bags * 256;
    init_out_kernel<<<(total + 255) / 256, 256, 0, stream>>>(cat, out, total);

    const int nchunks = (n_idx + CHUNK - 1) / CHUNK;   // 16384 waves
    const int blocks  = (nchunks + 3) / 4;             // 4096
    embag_kernel<<<blocks, 256, 0, stream>>>(
        wq, scales, biases, idx32, off32, out, num_bags, n_idx);
}